// Round 1
// 442.110 us; speedup vs baseline: 1.0183x; 1.0183x over previous
//
#include <hip/hip_runtime.h>

// Problem constants
#define Bn 256
#define Vn 512
#define Fn 256
// O = 2 hard-coded throughout.

// Workspace layout (bytes):
//   packed adjacency bits: [Bn*Vn][8] uint64  at 0        (8 MB)
//   dinv:                  [Bn*Vn] float      at 8388608   (512 KB)
//   Y = X@W:               [Bn*Vn] float2     at 8912896   (1 MB)
#define WS_PACKED_OFF 0
#define WS_DINV_OFF   8388608
#define WS_Y_OFF      8912896

// Fused kernel: one wave (64 lanes) per row (b*Vn + v).
//   Graphs row (512 int32 = 2 KB) loaded as 2x int4 per lane (16 B/lane/instr).
//   Bit packing uses a PERMUTED order: word j = q*4+c (q in {0,1}, c in {0..3}),
//   bit L of word j <-> element 256*q + 4*L + c.  Degree (popcount) is
//   order-invariant; the aggregation kernel unpacks in the same order.
//   Features row (256 f32 = 1 KB) loaded as float4 per lane; dot with W rows,
//   wave-reduced; both streams' loads issue together for max MLP.
__global__ __launch_bounds__(256) void fused_pack_xw_kernel(
    const int* __restrict__ G,
    const float* __restrict__ X,
    const float* __restrict__ W,
    unsigned long long* __restrict__ P,
    float* __restrict__ dinv,
    float2* __restrict__ Y) {
  int gid  = blockIdx.x * 256 + threadIdx.x;
  int row  = gid >> 6;          // b*Vn + v, wave-uniform
  int lane = gid & 63;
  int v    = row & (Vn - 1);

  // ---- issue all global loads up front (graphs + features + weights) ----
  const int4* g4 = (const int4*)(G + (size_t)row * Vn);
  int4 A0 = g4[lane];           // elements 4*lane   .. 4*lane+3
  int4 A1 = g4[64 + lane];      // elements 256+4*lane .. 256+4*lane+3

  const float4* xr = (const float4*)(X + (size_t)row * Fn);
  float4 x = xr[lane];
  const float4* wr = (const float4*)W;   // W is [F,2] row-major
  float4 w0 = wr[lane * 2];      // {W[4L][0],W[4L][1],W[4L+1][0],W[4L+1][1]}
  float4 w1 = wr[lane * 2 + 1];  // {W[4L+2][0],W[4L+2][1],W[4L+3][0],W[4L+3][1]}

  // ---- permuted ballots: word q*4+c, bit L <-> element 256q+4L+c ----
  unsigned long long m0 = __ballot(A0.x != 0);
  unsigned long long m1 = __ballot(A0.y != 0);
  unsigned long long m2 = __ballot(A0.z != 0);
  unsigned long long m3 = __ballot(A0.w != 0);
  unsigned long long m4 = __ballot(A1.x != 0);
  unsigned long long m5 = __ballot(A1.y != 0);
  unsigned long long m6 = __ballot(A1.z != 0);
  unsigned long long m7 = __ballot(A1.w != 0);

  // Force self-loop bit (diag = 1). Element v -> word (v>>8)*4 + (v&3),
  // bit (v>>2)&63.  All wave-uniform -> scalar branches.
  int widx = ((v >> 8) << 2) | (v & 3);
  unsigned long long db = 1ull << ((v >> 2) & 63);
  if      (widx == 0) m0 |= db;
  else if (widx == 1) m1 |= db;
  else if (widx == 2) m2 |= db;
  else if (widx == 3) m3 |= db;
  else if (widx == 4) m4 |= db;
  else if (widx == 5) m5 |= db;
  else if (widx == 6) m6 |= db;
  else                m7 |= db;

  int deg = __popcll(m0) + __popcll(m1) + __popcll(m2) + __popcll(m3) +
            __popcll(m4) + __popcll(m5) + __popcll(m6) + __popcll(m7);

  // ---- X @ W (O=2) ----
  float s0 = x.x * w0.x + x.y * w0.z + x.z * w1.x + x.w * w1.z;
  float s1 = x.x * w0.y + x.y * w0.w + x.z * w1.y + x.w * w1.w;
  #pragma unroll
  for (int off = 32; off; off >>= 1) {
    s0 += __shfl_xor(s0, off);
    s1 += __shfl_xor(s1, off);
  }

  // Lane i (i<8) stores word i via unrolled cndmask chain.
  unsigned long long sel = m0;
  sel = (lane == 1) ? m1 : sel;
  sel = (lane == 2) ? m2 : sel;
  sel = (lane == 3) ? m3 : sel;
  sel = (lane == 4) ? m4 : sel;
  sel = (lane == 5) ? m5 : sel;
  sel = (lane == 6) ? m6 : sel;
  sel = (lane == 7) ? m7 : sel;
  if (lane < 8) P[(size_t)row * 8 + lane] = sel;
  if (lane == 0) {
    dinv[row] = rsqrtf((float)deg);
    Y[row] = make_float2(s0, s1);
  }
}

// Aggregation + bias + relu + head dot + sigmoid.  One block of 512 threads
// per batch element (8 waves -> 2 waves/SIMD at 1 block/CU).  Thread t owns
// row v = t.  LDS holds Y[b,w,:]*dinv[b,w]; bit k of word j = q*4+c maps to
// element 256q+4k+c (wave-uniform broadcast read, no conflicts).
__global__ __launch_bounds__(512) void agg_head_kernel(
    const unsigned long long* __restrict__ P,
    const float* __restrict__ dinv,
    const float2* __restrict__ Y,
    const float* __restrict__ lw,
    const float* __restrict__ lb,
    const float* __restrict__ cb,
    float* __restrict__ out) {
  __shared__ float2 ylds[Vn];
  __shared__ float wsum[8];

  int b = blockIdx.x;
  int t = threadIdx.x;          // = row v

  // Stage Y * dinv[w] (fold column normalization).  Row norm reuses d below.
  float d;
  {
    d = dinv[b * Vn + t];
    float2 y = Y[b * Vn + t];
    ylds[t] = make_float2(y.x * d, y.y * d);
  }
  __syncthreads();

  // Preload this row's 8 mask words as 4x 16B loads (static extraction only).
  const ulonglong2* p2 = (const ulonglong2*)(P + ((size_t)b * Vn + t) * 8);

  float a0 = 0.f, a1 = 0.f;
  for (int jj = 0; jj < 4; ++jj) {
    ulonglong2 mm = p2[jj];
    #pragma unroll
    for (int h = 0; h < 2; ++h) {
      unsigned long long m = h ? mm.y : mm.x;
      int j = jj * 2 + h;                         // word index
      const float2* base = ylds + ((j >> 2) << 8) + (j & 3);
      unsigned lo = (unsigned)m;
      unsigned hi = (unsigned)(m >> 32);
      #pragma unroll
      for (int k = 0; k < 32; ++k) {
        float s = (float)((lo >> k) & 1u);        // v_bfe + v_cvt
        float2 y = base[4 * k];                   // uniform broadcast
        a0 = fmaf(s, y.x, a0);
        a1 = fmaf(s, y.y, a1);
      }
      #pragma unroll
      for (int k = 0; k < 32; ++k) {
        float s = (float)((hi >> k) & 1u);
        float2 y = base[4 * k + 128];
        a0 = fmaf(s, y.x, a0);
        a1 = fmaf(s, y.y, a1);
      }
    }
  }

  float cb0 = cb[0], cb1 = cb[1];
  const float2* lw2 = (const float2*)lw;          // lw flat index = v*2 + o
  float2 wv = lw2[t];

  float h0 = fmaxf(fmaf(d, a0, cb0), 0.f);
  float h1 = fmaxf(fmaf(d, a1, cb1), 0.f);
  float c = h0 * wv.x + h1 * wv.y;

  #pragma unroll
  for (int off = 32; off; off >>= 1) c += __shfl_xor(c, off);
  if ((t & 63) == 0) wsum[t >> 6] = c;
  __syncthreads();
  if (t == 0) {
    float logit = wsum[0] + wsum[1] + wsum[2] + wsum[3] +
                  wsum[4] + wsum[5] + wsum[6] + wsum[7] + lb[0];
    out[b] = 1.0f / (1.0f + expf(-logit));
  }
}

extern "C" void kernel_launch(void* const* d_in, const int* in_sizes, int n_in,
                              void* d_out, int out_size, void* d_ws, size_t ws_size,
                              hipStream_t stream) {
  const float* features = (const float*)d_in[0];
  const int*   graphs   = (const int*)d_in[1];
  const float* conv_w   = (const float*)d_in[2];
  const float* conv_b   = (const float*)d_in[3];
  const float* lin_w    = (const float*)d_in[4];
  const float* lin_b    = (const float*)d_in[5];
  float* out = (float*)d_out;

  char* ws = (char*)d_ws;
  unsigned long long* P = (unsigned long long*)(ws + WS_PACKED_OFF);
  float*  dinv = (float*)(ws + WS_DINV_OFF);
  float2* Y    = (float2*)(ws + WS_Y_OFF);

  // Fused pack+deg+XW: 131072 rows, one wave each -> 32768 blocks of 256
  fused_pack_xw_kernel<<<dim3(32768), dim3(256), 0, stream>>>(
      graphs, features, conv_w, P, dinv, Y);
  // Aggregation + head: one block of 512 per batch element
  agg_head_kernel<<<dim3(Bn), dim3(512), 0, stream>>>(
      P, dinv, Y, lin_w, lin_b, conv_b, out);
}